// Round 2
// baseline (468.155 us; speedup 1.0000x reference)
//
#include <hip/hip_runtime.h>

#define NN 100000
#define NE 600000
#define F  128
#define BN_EPS 1e-5f
#define TM 128
#define TK 32

// ---- detect int64 vs int32 edge_index ----
__global__ void k_detect(const unsigned* __restrict__ ei, int* __restrict__ flag)
{
    __shared__ int any;
    if (threadIdx.x == 0) any = 0;
    __syncthreads();
    unsigned v = ei[2 * threadIdx.x + 1];   // odd words: int64 high halves (all 0 if i64)
    if (v != 0u) atomicOr(&any, 1);
    __syncthreads();
    if (threadIdx.x == 0) *flag = (any == 0) ? 1 : 0;   // 1 => int64
}

__global__ void k_init(int* __restrict__ cnt, float* __restrict__ colsum, float* __restrict__ colsq)
{
    int i = blockIdx.x * 256 + threadIdx.x;
    if (i <= NN) cnt[i] = 0;
    if (i < F) { colsum[i] = 0.f; colsq[i] = 0.f; }
}

__global__ void k_count(const void* __restrict__ ei, const int* __restrict__ flag, int* __restrict__ cnt)
{
    int e = blockIdx.x * 256 + threadIdx.x;
    if (e >= NE) return;
    int col;
    if (*flag) col = (int)((const long long*)ei)[NE + e];
    else       col = ((const int*)ei)[NE + e];
    atomicAdd(&cnt[col], 1);
}

// ---- 3-kernel exclusive scan of cnt[0..NN] -> off[], cur[]; dinv fused here ----
__global__ void k_bsum(const int* __restrict__ cnt, int* __restrict__ bsum)
{
    __shared__ int s[256];
    int b = blockIdx.x, t = threadIdx.x;
    int i = b * 256 + t;
    s[t] = (i <= NN) ? cnt[i] : 0;
    __syncthreads();
    for (int o = 128; o > 0; o >>= 1) {
        if (t < o) s[t] += s[t + o];
        __syncthreads();
    }
    if (t == 0) bsum[b] = s[0];
}

__global__ void k_bscan(const int* __restrict__ bsum, int* __restrict__ bbase)
{
    __shared__ int s[512];
    int t = threadIdx.x;
    int v = (t < 391) ? bsum[t] : 0;
    s[t] = v;
    __syncthreads();
    for (int o = 1; o < 512; o <<= 1) {
        int tmp = (t >= o) ? s[t - o] : 0;
        __syncthreads();
        s[t] += tmp;
        __syncthreads();
    }
    if (t < 391) bbase[t] = s[t] - v;   // exclusive
}

__global__ void k_offsets(const int* __restrict__ cnt, const int* __restrict__ bbase,
                          int* __restrict__ off, int* __restrict__ cur,
                          float* __restrict__ dinv)
{
    __shared__ int s[256];
    int b = blockIdx.x, t = threadIdx.x;
    int i = b * 256 + t;
    int v = (i <= NN) ? cnt[i] : 0;
    s[t] = v;
    __syncthreads();
    for (int o = 1; o < 256; o <<= 1) {
        int tmp = (t >= o) ? s[t - o] : 0;
        __syncthreads();
        s[t] += tmp;
        __syncthreads();
    }
    int excl = s[t] - v + bbase[b];
    if (i <= NN) {
        off[i] = excl;
        if (i < NN) {
            cur[i] = excl;
            float d = (float)(v + 1);           // +1 self-loop
            float r = rsqrtf(d);
            r = r * (1.5f - 0.5f * d * r * r);  // Newton refine
            dinv[i] = r;
        }
    }
}

__global__ void k_place(const void* __restrict__ ei, const int* __restrict__ flag,
                        int* __restrict__ cur, int* __restrict__ csr)
{
    int e = blockIdx.x * 256 + threadIdx.x;
    if (e >= NE) return;
    int row, col;
    if (*flag) {
        row = (int)((const long long*)ei)[e];
        col = (int)((const long long*)ei)[NE + e];
    } else {
        row = ((const int*)ei)[e];
        col = ((const int*)ei)[NE + e];
    }
    int slot = atomicAdd(&cur[col], 1);
    csr[slot] = row;
}

// ---- pull aggregation: one node per wave64, float2 per lane, unroll-2 ----
__global__ __launch_bounds__(256) void k_agg(const float* __restrict__ x, const float* __restrict__ dinv,
                                             const int* __restrict__ off, const int* __restrict__ csr,
                                             float* __restrict__ aggx)
{
    int node = blockIdx.x * 4 + (threadIdx.x >> 6);
    int lane = threadIdx.x & 63;
    if (node >= NN) return;
    float di = dinv[node];
    float2 v = ((const float2*)(x + (size_t)node * F))[lane];
    float ax = v.x * di, ay = v.y * di;
    int e = off[node], e1 = off[node + 1];
    for (; e + 1 < e1; e += 2) {
        int r0 = csr[e], r1 = csr[e + 1];
        float s0 = dinv[r0], s1 = dinv[r1];
        float2 u0 = ((const float2*)(x + (size_t)r0 * F))[lane];
        float2 u1 = ((const float2*)(x + (size_t)r1 * F))[lane];
        ax = fmaf(u0.x, s0, ax); ay = fmaf(u0.y, s0, ay);
        ax = fmaf(u1.x, s1, ax); ay = fmaf(u1.y, s1, ay);
    }
    if (e < e1) {
        int r = csr[e]; float s = dinv[r];
        float2 u = ((const float2*)(x + (size_t)r * F))[lane];
        ax = fmaf(u.x, s, ax); ay = fmaf(u.y, s, ay);
    }
    float2 o; o.x = ax * di; o.y = ay * di;
    ((float2*)(aggx + (size_t)node * F))[lane] = o;
}

// ---- GEMM: blockIdx.y==0 : r = relu(aggx@W + b) in-place into aggx, + BN partials
//            blockIdx.y==1 : out = x@Wr + br
//      tile 128 rows x 128 cols, microtile 16x4, LDS 32KB -> 4 blocks/CU ----
__global__ __launch_bounds__(256, 4) void k_gemm2(
    float* __restrict__ A, const float* __restrict__ X,
    const float* __restrict__ W, const float* __restrict__ Wr,
    const float* __restrict__ bias, const float* __restrict__ biasr,
    float* __restrict__ out, float* __restrict__ colsum, float* __restrict__ colsq)
{
    __shared__ float At[TM][TK];    // 16 KB
    __shared__ float Wt[TK][F];     // 16 KB

    const int tid = threadIdx.x;
    const int tx = tid & 31;        // cols 4*tx..+3
    const int ty = tid >> 5;        // rows ty*16..+15
    const int type = blockIdx.y;
    const int r0 = blockIdx.x * TM;
    const float* __restrict__ src = type ? X : (const float*)A;
    const float* __restrict__ wm  = type ? Wr : W;

    float4 acc[16];
#pragma unroll
    for (int i = 0; i < 16; ++i) acc[i] = make_float4(0.f, 0.f, 0.f, 0.f);

    for (int kc = 0; kc < 4; ++kc) {
        __syncthreads();
        // stage A-chunk [128 rows][32 k] : 1024 float4s
#pragma unroll
        for (int it = 0; it < 4; ++it) {
            int idx = tid + it * 256;       // 0..1023
            int row = idx >> 3;
            int slot = idx & 7;
            int gr = r0 + row;
            float4 v = make_float4(0.f, 0.f, 0.f, 0.f);
            if (gr < NN) v = *(const float4*)(src + (size_t)gr * F + kc * TK + slot * 4);
            *(float4*)(&At[row][slot * 4]) = v;
        }
        // stage W-chunk [32 k][128 j] : 1024 float4s
#pragma unroll
        for (int it = 0; it < 4; ++it) {
            int idx = tid + it * 256;
            int kr = idx >> 5;
            int jc = (idx & 31) << 2;
            *(float4*)(&Wt[kr][jc]) = *(const float4*)(wm + (size_t)(kc * TK + kr) * F + jc);
        }
        __syncthreads();
#pragma unroll
        for (int kq = 0; kq < 8; ++kq) {
            float4 w0 = *(const float4*)(&Wt[kq * 4 + 0][tx * 4]);
            float4 w1 = *(const float4*)(&Wt[kq * 4 + 1][tx * 4]);
            float4 w2 = *(const float4*)(&Wt[kq * 4 + 2][tx * 4]);
            float4 w3 = *(const float4*)(&Wt[kq * 4 + 3][tx * 4]);
#pragma unroll
            for (int i = 0; i < 16; ++i) {
                float4 a = *(const float4*)(&At[ty * 16 + i][kq * 4]);
                acc[i].x = fmaf(a.x, w0.x, acc[i].x);
                acc[i].y = fmaf(a.x, w0.y, acc[i].y);
                acc[i].z = fmaf(a.x, w0.z, acc[i].z);
                acc[i].w = fmaf(a.x, w0.w, acc[i].w);
                acc[i].x = fmaf(a.y, w1.x, acc[i].x);
                acc[i].y = fmaf(a.y, w1.y, acc[i].y);
                acc[i].z = fmaf(a.y, w1.z, acc[i].z);
                acc[i].w = fmaf(a.y, w1.w, acc[i].w);
                acc[i].x = fmaf(a.z, w2.x, acc[i].x);
                acc[i].y = fmaf(a.z, w2.y, acc[i].y);
                acc[i].z = fmaf(a.z, w2.z, acc[i].z);
                acc[i].w = fmaf(a.z, w2.w, acc[i].w);
                acc[i].x = fmaf(a.w, w3.x, acc[i].x);
                acc[i].y = fmaf(a.w, w3.y, acc[i].y);
                acc[i].z = fmaf(a.w, w3.z, acc[i].z);
                acc[i].w = fmaf(a.w, w3.w, acc[i].w);
            }
        }
    }
    __syncthreads();

    if (type == 0) {
        float* ssum = &Wt[0][0];        // reuse weight LDS for stats
        float* ssq  = &Wt[0][0] + F;
        if (tid < F) { ssum[tid] = 0.f; ssq[tid] = 0.f; }
        __syncthreads();
        float4 bv = *(const float4*)(bias + tx * 4);
        float ls[4] = {0.f, 0.f, 0.f, 0.f};
        float lq[4] = {0.f, 0.f, 0.f, 0.f};
#pragma unroll
        for (int i = 0; i < 16; ++i) {
            int gr = r0 + ty * 16 + i;
            if (gr < NN) {
                float r0_ = fmaxf(acc[i].x + bv.x, 0.f);
                float r1_ = fmaxf(acc[i].y + bv.y, 0.f);
                float r2_ = fmaxf(acc[i].z + bv.z, 0.f);
                float r3_ = fmaxf(acc[i].w + bv.w, 0.f);
                ls[0] += r0_; lq[0] = fmaf(r0_, r0_, lq[0]);
                ls[1] += r1_; lq[1] = fmaf(r1_, r1_, lq[1]);
                ls[2] += r2_; lq[2] = fmaf(r2_, r2_, lq[2]);
                ls[3] += r3_; lq[3] = fmaf(r3_, r3_, lq[3]);
                *(float4*)(A + (size_t)gr * F + tx * 4) = make_float4(r0_, r1_, r2_, r3_);
            }
        }
#pragma unroll
        for (int j = 0; j < 4; ++j) {
            atomicAdd(&ssum[tx * 4 + j], ls[j]);
            atomicAdd(&ssq[tx * 4 + j], lq[j]);
        }
        __syncthreads();
        if (tid < F) {
            atomicAdd(&colsum[tid], ssum[tid]);
            atomicAdd(&colsq[tid], ssq[tid]);
        }
    } else {
        float4 bv = *(const float4*)(biasr + tx * 4);
#pragma unroll
        for (int i = 0; i < 16; ++i) {
            int gr = r0 + ty * 16 + i;
            if (gr < NN) {
                *(float4*)(out + (size_t)gr * F + tx * 4) =
                    make_float4(acc[i].x + bv.x, acc[i].y + bv.y,
                                acc[i].z + bv.z, acc[i].w + bv.w);
            }
        }
    }
}

__global__ void k_stats(const float* __restrict__ colsum, const float* __restrict__ colsq,
                        const float* __restrict__ gamma, const float* __restrict__ beta,
                        float* __restrict__ scale, float* __restrict__ shift)
{
    int c = threadIdx.x;
    if (c < F) {
        float inv_n = 1.0f / (float)NN;
        float mean = colsum[c] * inv_n;
        float ex2  = colsq[c] * inv_n;
        float var  = fmaxf(ex2 - mean * mean, 0.f);
        float d = var + BN_EPS;
        float is = rsqrtf(d);
        is = is * (1.5f - 0.5f * d * is * is);   // Newton refine
        float sc = gamma[c] * is;
        scale[c] = sc;
        shift[c] = beta[c] - sc * mean;
    }
}

// out = r*scale[c] + shift[c] + res   (res already in d_out)
__global__ __launch_bounds__(256) void k_final(const float* __restrict__ r,
                                               const float* __restrict__ scale,
                                               const float* __restrict__ shift,
                                               float* __restrict__ out)
{
    int idx = blockIdx.x * 256 + threadIdx.x;   // float4 index, 3.2M total (exact)
    int c4 = idx & 31;
    float4 rv = ((const float4*)r)[idx];
    float4 ov = ((float4*)out)[idx];
    float4 sv = ((const float4*)scale)[c4];
    float4 hv = ((const float4*)shift)[c4];
    float4 o;
    o.x = fmaf(rv.x, sv.x, hv.x) + ov.x;
    o.y = fmaf(rv.y, sv.y, hv.y) + ov.y;
    o.z = fmaf(rv.z, sv.z, hv.z) + ov.z;
    o.w = fmaf(rv.w, sv.w, hv.w) + ov.w;
    ((float4*)out)[idx] = o;
}

extern "C" void kernel_launch(void* const* d_in, const int* in_sizes, int n_in,
                              void* d_out, int out_size, void* d_ws, size_t ws_size,
                              hipStream_t stream)
{
    (void)in_sizes; (void)n_in; (void)out_size; (void)ws_size;
    const float* x     = (const float*)d_in[0];
    const void*  ei    = d_in[1];
    const float* W     = (const float*)d_in[2];
    const float* b     = (const float*)d_in[3];
    const float* gamma = (const float*)d_in[4];
    const float* beta  = (const float*)d_in[5];
    const float* Wres  = (const float*)d_in[6];
    const float* bres  = (const float*)d_in[7];
    float* out = (float*)d_out;

    char* w = (char*)d_ws;
    float* aggx   = (float*)(w + 0);            // 51,200,000 B
    int*   cnt    = (int*)  (w + 51200000);
    float* dinv   = (float*)(w + 51600128);
    int*   off    = (int*)  (w + 52000256);
    int*   cur    = (int*)  (w + 52400384);
    int*   csr    = (int*)  (w + 52800512);
    int*   bsum   = (int*)  (w + 55200512);
    int*   bbase  = (int*)  (w + 55202176);
    float* colsum = (float*)(w + 55203840);
    float* colsq  = (float*)(w + 55204352);
    float* scale  = (float*)(w + 55204864);
    float* shift  = (float*)(w + 55205376);
    int*   flag   = (int*)  (w + 55205888);

    const int G_INIT = 392;
    const int G_E    = (NE + 255) / 256;        // 2344
    const int G_N    = 391;
    const int G_AGG  = (NN + 3) / 4;            // 25000
    const dim3 G_GEMM((NN + TM - 1) / TM, 2);   // (782, 2)
    const int G_FIN  = (NN * F / 4) / 256;      // 12500 exact

    k_detect <<<1, 256, 0, stream>>>((const unsigned*)ei, flag);
    k_init   <<<G_INIT, 256, 0, stream>>>(cnt, colsum, colsq);
    k_count  <<<G_E, 256, 0, stream>>>(ei, flag, cnt);
    k_bsum   <<<G_N, 256, 0, stream>>>(cnt, bsum);
    k_bscan  <<<1, 512, 0, stream>>>(bsum, bbase);
    k_offsets<<<G_N, 256, 0, stream>>>(cnt, bbase, off, cur, dinv);
    k_place  <<<G_E, 256, 0, stream>>>(ei, flag, cur, csr);
    k_agg    <<<G_AGG, 256, 0, stream>>>(x, dinv, off, csr, aggx);
    k_gemm2  <<<G_GEMM, 256, 0, stream>>>(aggx, x, W, Wres, b, bres, out, colsum, colsq);
    k_stats  <<<1, 128, 0, stream>>>(colsum, colsq, gamma, beta, scale, shift);
    k_final  <<<G_FIN, 256, 0, stream>>>(aggx, scale, shift, out);
}

// Round 4
// 369.190 us; speedup vs baseline: 1.2681x; 1.2681x over previous
//
#include <hip/hip_runtime.h>

#define NN 100000
#define NE 600000
#define F  128
#define BN_EPS 1e-5f
#define TM 128
#define TK 32

// ---- detect int64 vs int32 edge_index ----
__global__ void k_detect(const unsigned* __restrict__ ei, int* __restrict__ flag)
{
    __shared__ int any;
    if (threadIdx.x == 0) any = 0;
    __syncthreads();
    unsigned v = ei[2 * threadIdx.x + 1];   // odd words: int64 high halves (all 0 if i64)
    if (v != 0u) atomicOr(&any, 1);
    __syncthreads();
    if (threadIdx.x == 0) *flag = (any == 0) ? 1 : 0;   // 1 => int64
}

__global__ void k_init(int* __restrict__ cnt, float* __restrict__ colsum, float* __restrict__ colsq)
{
    int i = blockIdx.x * 256 + threadIdx.x;
    if (i <= NN) cnt[i] = 0;
    if (i < F) { colsum[i] = 0.f; colsq[i] = 0.f; }
}

__global__ void k_count(const void* __restrict__ ei, const int* __restrict__ flag, int* __restrict__ cnt)
{
    int e = blockIdx.x * 256 + threadIdx.x;
    if (e >= NE) return;
    int col;
    if (*flag) col = (int)((const long long*)ei)[NE + e];
    else       col = ((const int*)ei)[NE + e];
    atomicAdd(&cnt[col], 1);
}

// ---- 3-kernel exclusive scan of cnt[0..NN] -> off[], cur[]; dinv fused here ----
__global__ void k_bsum(const int* __restrict__ cnt, int* __restrict__ bsum)
{
    __shared__ int s[256];
    int b = blockIdx.x, t = threadIdx.x;
    int i = b * 256 + t;
    s[t] = (i <= NN) ? cnt[i] : 0;
    __syncthreads();
    for (int o = 128; o > 0; o >>= 1) {
        if (t < o) s[t] += s[t + o];
        __syncthreads();
    }
    if (t == 0) bsum[b] = s[0];
}

__global__ void k_bscan(const int* __restrict__ bsum, int* __restrict__ bbase)
{
    __shared__ int s[512];
    int t = threadIdx.x;
    int v = (t < 391) ? bsum[t] : 0;
    s[t] = v;
    __syncthreads();
    for (int o = 1; o < 512; o <<= 1) {
        int tmp = (t >= o) ? s[t - o] : 0;
        __syncthreads();
        s[t] += tmp;
        __syncthreads();
    }
    if (t < 391) bbase[t] = s[t] - v;   // exclusive
}

__global__ void k_offsets(const int* __restrict__ cnt, const int* __restrict__ bbase,
                          int* __restrict__ off, int* __restrict__ cur,
                          float* __restrict__ dinv)
{
    __shared__ int s[256];
    int b = blockIdx.x, t = threadIdx.x;
    int i = b * 256 + t;
    int v = (i <= NN) ? cnt[i] : 0;
    s[t] = v;
    __syncthreads();
    for (int o = 1; o < 256; o <<= 1) {
        int tmp = (t >= o) ? s[t - o] : 0;
        __syncthreads();
        s[t] += tmp;
        __syncthreads();
    }
    int excl = s[t] - v + bbase[b];
    if (i <= NN) {
        off[i] = excl;
        if (i < NN) {
            cur[i] = excl;
            float d = (float)(v + 1);           // +1 self-loop
            float r = rsqrtf(d);
            r = r * (1.5f - 0.5f * d * r * r);  // Newton refine
            dinv[i] = r;
        }
    }
}

__global__ void k_place(const void* __restrict__ ei, const int* __restrict__ flag,
                        int* __restrict__ cur, int* __restrict__ csr)
{
    int e = blockIdx.x * 256 + threadIdx.x;
    if (e >= NE) return;
    int row, col;
    if (*flag) {
        row = (int)((const long long*)ei)[e];
        col = (int)((const long long*)ei)[NE + e];
    } else {
        row = ((const int*)ei)[e];
        col = ((const int*)ei)[NE + e];
    }
    int slot = atomicAdd(&cur[col], 1);
    csr[slot] = row;
}

// ---- pull aggregation: one node per wave64, float2 per lane, unroll-4 ----
__global__ __launch_bounds__(256) void k_agg(const float* __restrict__ x, const float* __restrict__ dinv,
                                             const int* __restrict__ off, const int* __restrict__ csr,
                                             float* __restrict__ aggx)
{
    int node = blockIdx.x * 4 + (threadIdx.x >> 6);
    int lane = threadIdx.x & 63;
    if (node >= NN) return;
    float di = dinv[node];
    float2 v = ((const float2*)(x + (size_t)node * F))[lane];
    float ax = v.x * di, ay = v.y * di;
    int e = off[node], e1 = off[node + 1];
    for (; e + 4 <= e1; e += 4) {
        int r0 = csr[e], r1 = csr[e + 1], r2 = csr[e + 2], r3 = csr[e + 3];
        float s0 = dinv[r0], s1 = dinv[r1], s2 = dinv[r2], s3 = dinv[r3];
        float2 u0 = ((const float2*)(x + (size_t)r0 * F))[lane];
        float2 u1 = ((const float2*)(x + (size_t)r1 * F))[lane];
        float2 u2 = ((const float2*)(x + (size_t)r2 * F))[lane];
        float2 u3 = ((const float2*)(x + (size_t)r3 * F))[lane];
        ax = fmaf(u0.x, s0, ax); ay = fmaf(u0.y, s0, ay);
        ax = fmaf(u1.x, s1, ax); ay = fmaf(u1.y, s1, ay);
        ax = fmaf(u2.x, s2, ax); ay = fmaf(u2.y, s2, ay);
        ax = fmaf(u3.x, s3, ax); ay = fmaf(u3.y, s3, ay);
    }
    for (; e < e1; ++e) {
        int r = csr[e]; float s = dinv[r];
        float2 u = ((const float2*)(x + (size_t)r * F))[lane];
        ax = fmaf(u.x, s, ax); ay = fmaf(u.y, s, ay);
    }
    float2 o; o.x = ax * di; o.y = ay * di;
    ((float2*)(aggx + (size_t)node * F))[lane] = o;
}

// ---- GEMM: blockIdx.y==0 : r = relu(aggx@W + b) in-place into aggx, + BN partials
//            blockIdx.y==1 : out = x@Wr + br
//      tile 128 rows x 128 cols, microtile 16x4, LDS 32KB ----
// launch_bounds(256,2): do NOT force 4 blocks/CU — round 2 showed that caps
// VGPR at 64 and spills the 64-float accumulator to scratch (+250MB HBM).
__global__ __launch_bounds__(256, 2) void k_gemm2(
    float* __restrict__ A, const float* __restrict__ X,
    const float* __restrict__ W, const float* __restrict__ Wr,
    const float* __restrict__ bias, const float* __restrict__ biasr,
    float* __restrict__ out, float* __restrict__ colsum, float* __restrict__ colsq)
{
    __shared__ float At[TM][TK];    // 16 KB
    __shared__ float Wt[TK][F];     // 16 KB

    const int tid = threadIdx.x;
    const int tx = tid & 31;        // cols 4*tx..+3
    const int ty = tid >> 5;        // rows ty*16..+15
    const int type = blockIdx.y;
    const int r0 = blockIdx.x * TM;
    const float* __restrict__ src = type ? X : (const float*)A;
    const float* __restrict__ wm  = type ? Wr : W;

    float4 acc[16];
#pragma unroll
    for (int i = 0; i < 16; ++i) acc[i] = make_float4(0.f, 0.f, 0.f, 0.f);

    for (int kc = 0; kc < 4; ++kc) {
        __syncthreads();
        // stage A-chunk [128 rows][32 k] : 1024 float4s
#pragma unroll
        for (int it = 0; it < 4; ++it) {
            int idx = tid + it * 256;       // 0..1023
            int row = idx >> 3;
            int slot = idx & 7;
            int gr = r0 + row;
            float4 v = make_float4(0.f, 0.f, 0.f, 0.f);
            if (gr < NN) v = *(const float4*)(src + (size_t)gr * F + kc * TK + slot * 4);
            *(float4*)(&At[row][slot * 4]) = v;
        }
        // stage W-chunk [32 k][128 j] : 1024 float4s
#pragma unroll
        for (int it = 0; it < 4; ++it) {
            int idx = tid + it * 256;
            int kr = idx >> 5;
            int jc = (idx & 31) << 2;
            *(float4*)(&Wt[kr][jc]) = *(const float4*)(wm + (size_t)(kc * TK + kr) * F + jc);
        }
        __syncthreads();
#pragma unroll
        for (int kq = 0; kq < 8; ++kq) {
            float4 w0 = *(const float4*)(&Wt[kq * 4 + 0][tx * 4]);
            float4 w1 = *(const float4*)(&Wt[kq * 4 + 1][tx * 4]);
            float4 w2 = *(const float4*)(&Wt[kq * 4 + 2][tx * 4]);
            float4 w3 = *(const float4*)(&Wt[kq * 4 + 3][tx * 4]);
#pragma unroll
            for (int i = 0; i < 16; ++i) {
                float4 a = *(const float4*)(&At[ty * 16 + i][kq * 4]);
                acc[i].x = fmaf(a.x, w0.x, acc[i].x);
                acc[i].y = fmaf(a.x, w0.y, acc[i].y);
                acc[i].z = fmaf(a.x, w0.z, acc[i].z);
                acc[i].w = fmaf(a.x, w0.w, acc[i].w);
                acc[i].x = fmaf(a.y, w1.x, acc[i].x);
                acc[i].y = fmaf(a.y, w1.y, acc[i].y);
                acc[i].z = fmaf(a.y, w1.z, acc[i].z);
                acc[i].w = fmaf(a.y, w1.w, acc[i].w);
                acc[i].x = fmaf(a.z, w2.x, acc[i].x);
                acc[i].y = fmaf(a.z, w2.y, acc[i].y);
                acc[i].z = fmaf(a.z, w2.z, acc[i].z);
                acc[i].w = fmaf(a.z, w2.w, acc[i].w);
                acc[i].x = fmaf(a.w, w3.x, acc[i].x);
                acc[i].y = fmaf(a.w, w3.y, acc[i].y);
                acc[i].z = fmaf(a.w, w3.z, acc[i].z);
                acc[i].w = fmaf(a.w, w3.w, acc[i].w);
            }
        }
    }
    __syncthreads();

    if (type == 0) {
        float* ssum = &Wt[0][0];        // reuse weight LDS for stats
        float* ssq  = &Wt[0][0] + F;
        if (tid < F) { ssum[tid] = 0.f; ssq[tid] = 0.f; }
        __syncthreads();
        float4 bv = *(const float4*)(bias + tx * 4);
        float ls[4] = {0.f, 0.f, 0.f, 0.f};
        float lq[4] = {0.f, 0.f, 0.f, 0.f};
#pragma unroll
        for (int i = 0; i < 16; ++i) {
            int gr = r0 + ty * 16 + i;
            if (gr < NN) {
                float r0_ = fmaxf(acc[i].x + bv.x, 0.f);
                float r1_ = fmaxf(acc[i].y + bv.y, 0.f);
                float r2_ = fmaxf(acc[i].z + bv.z, 0.f);
                float r3_ = fmaxf(acc[i].w + bv.w, 0.f);
                ls[0] += r0_; lq[0] = fmaf(r0_, r0_, lq[0]);
                ls[1] += r1_; lq[1] = fmaf(r1_, r1_, lq[1]);
                ls[2] += r2_; lq[2] = fmaf(r2_, r2_, lq[2]);
                ls[3] += r3_; lq[3] = fmaf(r3_, r3_, lq[3]);
                *(float4*)(A + (size_t)gr * F + tx * 4) = make_float4(r0_, r1_, r2_, r3_);
            }
        }
#pragma unroll
        for (int j = 0; j < 4; ++j) {
            atomicAdd(&ssum[tx * 4 + j], ls[j]);
            atomicAdd(&ssq[tx * 4 + j], lq[j]);
        }
        __syncthreads();
        if (tid < F) {
            atomicAdd(&colsum[tid], ssum[tid]);
            atomicAdd(&colsq[tid], ssq[tid]);
        }
    } else {
        float4 bv = *(const float4*)(biasr + tx * 4);
#pragma unroll
        for (int i = 0; i < 16; ++i) {
            int gr = r0 + ty * 16 + i;
            if (gr < NN) {
                *(float4*)(out + (size_t)gr * F + tx * 4) =
                    make_float4(acc[i].x + bv.x, acc[i].y + bv.y,
                                acc[i].z + bv.z, acc[i].w + bv.w);
            }
        }
    }
}

__global__ void k_stats(const float* __restrict__ colsum, const float* __restrict__ colsq,
                        const float* __restrict__ gamma, const float* __restrict__ beta,
                        float* __restrict__ scale, float* __restrict__ shift)
{
    int c = threadIdx.x;
    if (c < F) {
        float inv_n = 1.0f / (float)NN;
        float mean = colsum[c] * inv_n;
        float ex2  = colsq[c] * inv_n;
        float var  = fmaxf(ex2 - mean * mean, 0.f);
        float d = var + BN_EPS;
        float is = rsqrtf(d);
        is = is * (1.5f - 0.5f * d * is * is);   // Newton refine
        float sc = gamma[c] * is;
        scale[c] = sc;
        shift[c] = beta[c] - sc * mean;
    }
}

// out = r*scale[c] + shift[c] + res   (res already in d_out)
__global__ __launch_bounds__(256) void k_final(const float* __restrict__ r,
                                               const float* __restrict__ scale,
                                               const float* __restrict__ shift,
                                               float* __restrict__ out)
{
    int idx = blockIdx.x * 256 + threadIdx.x;   // float4 index, 3.2M total (exact)
    int c4 = idx & 31;
    float4 rv = ((const float4*)r)[idx];
    float4 ov = ((float4*)out)[idx];
    float4 sv = ((const float4*)scale)[c4];
    float4 hv = ((const float4*)shift)[c4];
    float4 o;
    o.x = fmaf(rv.x, sv.x, hv.x) + ov.x;
    o.y = fmaf(rv.y, sv.y, hv.y) + ov.y;
    o.z = fmaf(rv.z, sv.z, hv.z) + ov.z;
    o.w = fmaf(rv.w, sv.w, hv.w) + ov.w;
    ((float4*)out)[idx] = o;
}

extern "C" void kernel_launch(void* const* d_in, const int* in_sizes, int n_in,
                              void* d_out, int out_size, void* d_ws, size_t ws_size,
                              hipStream_t stream)
{
    (void)in_sizes; (void)n_in; (void)out_size; (void)ws_size;
    const float* x     = (const float*)d_in[0];
    const void*  ei    = d_in[1];
    const float* W     = (const float*)d_in[2];
    const float* b     = (const float*)d_in[3];
    const float* gamma = (const float*)d_in[4];
    const float* beta  = (const float*)d_in[5];
    const float* Wres  = (const float*)d_in[6];
    const float* bres  = (const float*)d_in[7];
    float* out = (float*)d_out;

    char* w = (char*)d_ws;
    float* aggx   = (float*)(w + 0);            // 51,200,000 B
    int*   cnt    = (int*)  (w + 51200000);
    float* dinv   = (float*)(w + 51600128);
    int*   off    = (int*)  (w + 52000256);
    int*   cur    = (int*)  (w + 52400384);
    int*   csr    = (int*)  (w + 52800512);
    int*   bsum   = (int*)  (w + 55200512);
    int*   bbase  = (int*)  (w + 55202176);
    float* colsum = (float*)(w + 55203840);
    float* colsq  = (float*)(w + 55204352);
    float* scale  = (float*)(w + 55204864);
    float* shift  = (float*)(w + 55205376);
    int*   flag   = (int*)  (w + 55205888);

    const int G_INIT = 392;
    const int G_E    = (NE + 255) / 256;        // 2344
    const int G_N    = 391;
    const int G_AGG  = (NN + 3) / 4;            // 25000
    const dim3 G_GEMM((NN + TM - 1) / TM, 2);   // (782, 2)
    const int G_FIN  = (NN * F / 4) / 256;      // 12500 exact

    k_detect <<<1, 256, 0, stream>>>((const unsigned*)ei, flag);
    k_init   <<<G_INIT, 256, 0, stream>>>(cnt, colsum, colsq);
    k_count  <<<G_E, 256, 0, stream>>>(ei, flag, cnt);
    k_bsum   <<<G_N, 256, 0, stream>>>(cnt, bsum);
    k_bscan  <<<1, 512, 0, stream>>>(bsum, bbase);
    k_offsets<<<G_N, 256, 0, stream>>>(cnt, bbase, off, cur, dinv);
    k_place  <<<G_E, 256, 0, stream>>>(ei, flag, cur, csr);
    k_agg    <<<G_AGG, 256, 0, stream>>>(x, dinv, off, csr, aggx);
    k_gemm2  <<<G_GEMM, 256, 0, stream>>>(aggx, x, W, Wres, b, bres, out, colsum, colsq);
    k_stats  <<<1, 128, 0, stream>>>(colsum, colsq, gamma, beta, scale, shift);
    k_final  <<<G_FIN, 256, 0, stream>>>(aggx, scale, shift, out);
}